// Round 10
// baseline (126.870 us; speedup 1.0000x reference)
//
#include <hip/hip_runtime.h>
#include <hip/hip_bf16.h>

namespace {

constexpr int MM = 64;
constexpr int KK = 4096;
constexpr int NN = 11008;
constexpr int NZROW = NN / 8;    // 1376
constexpr int NTILES = NN / 128; // 86
constexpr int NCHT = KK / 32;    // 128 chunks of 32 k

typedef float f32x4 __attribute__((ext_vector_type(4)));
typedef short s16x8 __attribute__((ext_vector_type(8)));
typedef int   i32x4 __attribute__((ext_vector_type(4)));

// truncating bf16 pack of (even,odd) -> one dword, 1 instr
__device__ __forceinline__ int perm_trunc(float even, float odd) {
  return (int)__builtin_amdgcn_perm(__float_as_uint(odd), __float_as_uint(even), 0x07060302u);
}
// RNE bf16 pack
__device__ __forceinline__ unsigned rne_adj(float f) {
  unsigned u = __float_as_uint(f);
  return u + 0x7FFFu + ((u >> 16) & 1u);
}
__device__ __forceinline__ int pack_rne(float even, float odd) {
  return (int)__builtin_amdgcn_perm(rne_adj(odd), rne_adj(even), 0x07060302u);
}

// x pre-converted to bf16, fragment-ready: xT8[kblk][m][j] = bf16(x[m][kblk*8+j]).
// 512 KB in device BSS — not harness-poisoned, rebuilt every call (same work).
__device__ short g_xT8[KK * MM];

__global__ __launch_bounds__(256) void xt8_kernel(const float* __restrict__ x)
{
  const int m    = blockIdx.x >> 1;
  const int kblk = (blockIdx.x & 1) * 256 + threadIdx.x;
  const float* p = x + m * KK + kblk * 8;
  const f32x4 a = *(const f32x4*)p;
  const f32x4 b = *(const f32x4*)(p + 4);
  i32x4 w;
  w.x = pack_rne(a.x, a.y);
  w.y = pack_rne(a.z, a.w);
  w.z = pack_rne(b.x, b.y);
  w.w = pack_rne(b.z, b.w);
  *(i32x4*)(g_xT8 + ((size_t)kblk * MM + m) * 8) = w;
}

// R10: single-dispatch GEMM. 86 blocks x 512 thr (8 waves; 1 block/CU,
// 2 waves/SIMD). Wave owns 16 cols x full K: no split-k, no ws, no reduce,
// no LDS, no barriers, no atomics. Swapped operands (R9-verified):
//   A = dequantized W  (one qw dword == A-frag: row=lane&15 -> n, k=quad*8+j)
//   B = g_xT8 fragment (col=lane&15 -> m, k=quad*8+j), direct 16B loads
//   D: col=lane&15 -> m, row=quad*4+reg -> n-local
// Deep rolling prefetch: qw ring depth 8, B-frag depth 1, scale/zero depth 3.
// Loop unrolled x16 + peeled tail so ring indices/guards are compile-time.
__global__ __launch_bounds__(512, 2) void gptq_gemm_kernel(
    const int* __restrict__ qw, const int* __restrict__ qz,
    const float* __restrict__ scales, const float* __restrict__ bias,
    float* __restrict__ out)
{
  const int tid  = threadIdx.x;
  const int wave = tid >> 6;
  const int lane = tid & 63;
  const int ml   = lane & 15;
  const int quad = lane >> 4;

  const int nw0  = blockIdx.x * 128 + wave * 16;
  const int ncol = nw0 + ml;

  const int*   qwl = qw + (size_t)quad * NN + ncol;   // + g*4*NN per chunk
  const s16x8* xb  = (const s16x8*)g_xT8;
  const int    bb  = quad * MM + ml;                  // + g*4*MM per chunk, + mt*16

  f32x4 acc[4];
  #pragma unroll
  for (int i = 0; i < 4; ++i) acc[i] = {0.f, 0.f, 0.f, 0.f};

  int   qv[8];      // qw ring, depth 8 chunks
  s16x8 bf[2][4];   // B-frag ring, depth 1 chunk
  float ps[4];      // scale ring, depth 3 SC
  int   pzd[4];     // qzeros dword ring

  // ---- prologue ----
  #pragma unroll
  for (int i = 0; i < 8; ++i) qv[i] = qwl[(size_t)i * 4 * NN];
  #pragma unroll
  for (int mt = 0; mt < 4; ++mt) bf[0][mt] = xb[bb + mt * 16];
  #pragma unroll
  for (int s = 0; s < 3; ++s) {
    ps[s]  = scales[(size_t)s * NN + ncol];
    pzd[s] = qz[(size_t)s * NZROW + (ncol >> 3)];
  }

  // one chunk of 32 k; REFILL_Q / PF_B / PF_S are compile-time per instance
  auto chunk = [&](int g, bool refillQ, bool pfB, bool pfS) {
    const int v = qv[g & 7];                       // read before refill
    if (refillQ) qv[g & 7] = qwl[(size_t)(g + 8) * 4 * NN];
    if (pfB) {
      #pragma unroll
      for (int mt = 0; mt < 4; ++mt)
        bf[(g + 1) & 1][mt] = xb[bb + (size_t)(g + 1) * 4 * MM + mt * 16];
    }
    if (pfS) {
      const int gs3 = (g >> 2) + 3;
      ps[gs3 & 3]  = scales[(size_t)gs3 * NN + ncol];
      pzd[gs3 & 3] = qz[(size_t)gs3 * NZROW + (ncol >> 3)];
    }
    const int gs = g >> 2;
    const float s = ps[gs & 3];
    const float C = (float)(0x800000 + 1)
                  + (float)((pzd[gs & 3] >> ((ncol & 7) * 4)) & 15);
    // exact dequant: qf=(nib|0x4B000000)=2^23+q; d=qf-C (Sterbenz: q-z-1);
    // w=s*d; truncating bf16 pack
    const float w0 = s * (__int_as_float(((v      ) & 15) | 0x4B000000) - C);
    const float w1 = s * (__int_as_float(((v >>  4) & 15) | 0x4B000000) - C);
    const float w2 = s * (__int_as_float(((v >>  8) & 15) | 0x4B000000) - C);
    const float w3 = s * (__int_as_float(((v >> 12) & 15) | 0x4B000000) - C);
    const float w4 = s * (__int_as_float(((v >> 16) & 15) | 0x4B000000) - C);
    const float w5 = s * (__int_as_float(((v >> 20) & 15) | 0x4B000000) - C);
    const float w6 = s * (__int_as_float(((v >> 24) & 15) | 0x4B000000) - C);
    const float w7 = s * (__int_as_float(((v >> 28) & 15) | 0x4B000000) - C);
    i32x4 b;
    b.x = perm_trunc(w0, w1); b.y = perm_trunc(w2, w3);
    b.z = perm_trunc(w4, w5); b.w = perm_trunc(w6, w7);
    const s16x8 wf = __builtin_bit_cast(s16x8, b);
    #pragma unroll
    for (int mt = 0; mt < 4; ++mt)
      acc[mt] = __builtin_amdgcn_mfma_f32_16x16x32_bf16(wf, bf[g & 1][mt], acc[mt], 0, 0, 0);
  };

  // main: 7 trips x 16 chunks, all refills in range (g<=111: g+8<=119, gs3<=30)
  for (int base = 0; base < NCHT - 16; base += 16) {
    #pragma unroll
    for (int i = 0; i < 16; ++i)
      chunk(base + i, true, true, (i & 3) == 0);
  }
  // peeled tail: g = 112..127, guards compile-time
  #pragma unroll
  for (int i = 0; i < 16; ++i) {
    const int g = NCHT - 16 + i;
    chunk(g, i < 8, i < 15, i == 0);   // gs3=31 only at i==0
  }

  // ---- epilogue: bias + direct stores (16B per store) ----
  const f32x4 b4 = *(const f32x4*)(bias + nw0 + quad * 4);
  #pragma unroll
  for (int mt = 0; mt < 4; ++mt) {
    const f32x4 r = acc[mt] + b4;
    *(f32x4*)(out + (size_t)(mt * 16 + ml) * NN + nw0 + quad * 4) = r;
  }
}

} // namespace

extern "C" void kernel_launch(void* const* d_in, const int* in_sizes, int n_in,
                              void* d_out, int out_size, void* d_ws, size_t ws_size,
                              hipStream_t stream) {
  const float* x      = (const float*)d_in[0];
  const int*   qw     = (const int*)d_in[1];
  const int*   qz     = (const int*)d_in[2];
  const float* scales = (const float*)d_in[3];
  const float* bias   = (const float*)d_in[4];
  float* out = (float*)d_out;

  xt8_kernel<<<2 * MM, 256, 0, stream>>>(x);
  gptq_gemm_kernel<<<NTILES, 512, 0, stream>>>(qw, qz, scales, bias, out);
}

// Round 11
// 107.407 us; speedup vs baseline: 1.1812x; 1.1812x over previous
//
#include <hip/hip_runtime.h>
#include <hip/hip_bf16.h>

namespace {

constexpr int MM = 64;
constexpr int KK = 4096;
constexpr int NN = 11008;
constexpr int NZROW = NN / 8;     // 1376
constexpr int KSPLIT = 8;
constexpr int KSEG = KK / KSPLIT; // 512
constexpr int NTILES = NN / 128;  // 86
constexpr int NCH = KSEG / 32;    // 16 chunks per wave
constexpr int BLK_FLOATS = 64 * 128;   // 8192 partial floats per block
constexpr size_t WS_NEED = (size_t)NTILES * KSPLIT * BLK_FLOATS * 4;  // 22.5 MB

typedef float f32x4 __attribute__((ext_vector_type(4)));
typedef short s16x8 __attribute__((ext_vector_type(8)));
typedef int   i32x4 __attribute__((ext_vector_type(4)));

// truncating bf16 pack of (even,odd) -> one dword, 1 instr
__device__ __forceinline__ int perm_trunc(float even, float odd) {
  return (int)__builtin_amdgcn_perm(__float_as_uint(odd), __float_as_uint(even), 0x07060302u);
}
// RNE bf16 pack
__device__ __forceinline__ unsigned rne_adj(float f) {
  unsigned u = __float_as_uint(f);
  return u + 0x7FFFu + ((u >> 16) & 1u);
}
__device__ __forceinline__ int pack_rne(float even, float odd) {
  return (int)__builtin_amdgcn_perm(rne_adj(odd), rne_adj(even), 0x07060302u);
}

// x pre-converted to bf16, fragment-ready: xT8[kblk][m][j] = bf16(x[m][kblk*8+j]).
// 512 KB device BSS — not harness-poisoned; rebuilt every call (same work).
__device__ short g_xT8[KK * MM];

__global__ __launch_bounds__(256) void xt8_kernel(const float* __restrict__ x)
{
  const int m    = blockIdx.x >> 1;
  const int kblk = (blockIdx.x & 1) * 256 + threadIdx.x;
  const float* p = x + m * KK + kblk * 8;
  const f32x4 a = *(const f32x4*)p;
  const f32x4 b = *(const f32x4*)(p + 4);
  i32x4 w;
  w.x = pack_rne(a.x, a.y);
  w.y = pack_rne(a.z, a.w);
  w.z = pack_rne(b.x, b.y);
  w.w = pack_rne(b.z, b.w);
  *(i32x4*)(g_xT8 + ((size_t)kblk * MM + m) * 8) = w;
}

// fallback path only: out[m][n] = bias[n], atomics on top
__global__ __launch_bounds__(256) void prep_kernel(
    const float* __restrict__ bias, float* __restrict__ out)
{
  const int i = blockIdx.x * 256 + threadIdx.x;
  out[i] = bias[i % NN];
}

// un-permute + sum KSPLIT partials + bias (R9-verified mapping)
__global__ __launch_bounds__(256) void reduce_kernel(
    const float* __restrict__ ws, const float* __restrict__ bias,
    float* __restrict__ out)
{
  const int i4 = (blockIdx.x * 256 + threadIdx.x) * 4;
  const int m  = i4 / NN;
  const int n  = i4 - m * NN;
  const int ntile = n >> 7, nt = n & 127;
  const int wv = nt >> 5, ns = (nt >> 4) & 1, qd = (nt >> 2) & 3;
  const int mt = m >> 4,  ml = m & 15;
  const float* base = ws + (size_t)(ntile * KSPLIT) * BLK_FLOATS
                    + ((wv * 8 + ns * 4 + mt) * 64 + qd * 16 + ml) * 4;
  f32x4 sum = *(const f32x4*)(bias + n);
  #pragma unroll
  for (int p = 0; p < KSPLIT; ++p)
    sum += *(const f32x4*)(base + (size_t)p * BLK_FLOATS);
  *(f32x4*)(out + i4) = sum;
}

// R11: R9's parallelism (688 blocks, 4 waves x 32 cols, KSPLIT=8, all
// co-resident at (256,3)) + zero-LDS/zero-barrier innards + DEEP prefetch:
//   bf ring-4, lookahead 3 chunks (consumed frag ~3 chunks / ~24 loads old
//     -> waitcnt has slack; qw prefetches never drain)
//   qv ring-4, lookahead 4 chunks; scales/zeros ring-2, lookahead 1 group
// Swapped operands (R9/R10-verified): A = dequantized W (one qw dword ==
// A-frag), B = g_xT8 frags (16B loads). D: col=lane&15 -> m, row=quad*4+r -> n.
template<bool ATOMIC>
__global__ __launch_bounds__(256, 3) void gptq_gemm_kernel(
    const int* __restrict__ qw, const int* __restrict__ qz,
    const float* __restrict__ scales, float* __restrict__ outws)
{
  const int tid  = threadIdx.x;
  const int wave = tid >> 6;
  const int lane = tid & 63;
  const int ml   = lane & 15;
  const int quad = lane >> 4;

  const int ks    = blockIdx.x & 7;
  const int ntile = blockIdx.x >> 3;
  const int nw0   = ntile * 128 + wave * 32;
  const int ncol0 = nw0 + ml;
  const int rbase = ks * 64;               // qw dword-row base of this split

  const int* qwl = qw + (size_t)(rbase + quad) * NN + ncol0;  // col1 = +16
  const s16x8* xb = (const s16x8*)g_xT8;
  const int bb = (rbase + quad) * MM + ml;  // + g*256 per chunk, + mt*16
  const int g0 = ks * 4;                    // first quant group of split
  const int zsh = (ncol0 & 7) * 4;          // same for ncol0+16

  f32x4 acc[2][4];
  #pragma unroll
  for (int a = 0; a < 2; ++a)
    #pragma unroll
    for (int b = 0; b < 4; ++b) acc[a][b] = {0.f, 0.f, 0.f, 0.f};

  int   qv[4][2];     // qw ring-4 (lookahead 4)
  s16x8 bf[4][4];     // B-frag ring-4 (lookahead 3)
  float ps[2][2];     // scale ring-2 (lookahead 1 group)
  float Cs[2][2];     // 2^23 + z + 1 per (ring, col-frag)

  // ---- prologue ----
  #pragma unroll
  for (int i = 0; i < 4; ++i) {
    qv[i][0] = qwl[(size_t)i * 4 * NN];
    qv[i][1] = qwl[(size_t)i * 4 * NN + 16];
  }
  #pragma unroll
  for (int j = 0; j < 3; ++j)
    #pragma unroll
    for (int mt = 0; mt < 4; ++mt)
      bf[j][mt] = xb[bb + j * 256 + mt * 16];
  #pragma unroll
  for (int gl = 0; gl < 2; ++gl) {
    const int gg = g0 + gl;
    ps[gl][0] = scales[(size_t)gg * NN + ncol0];
    ps[gl][1] = scales[(size_t)gg * NN + ncol0 + 16];
    const int zd0 = qz[(size_t)gg * NZROW + (ncol0 >> 3)];
    const int zd1 = qz[(size_t)gg * NZROW + (ncol0 >> 3) + 2];
    Cs[gl][0] = (float)(0x800000 + 1) + (float)((zd0 >> zsh) & 15);
    Cs[gl][1] = (float)(0x800000 + 1) + (float)((zd1 >> zsh) & 15);
  }

  // ---- 16 chunks, fully unrolled (all ring indices compile-time) ----
  #pragma unroll
  for (int g = 0; g < NCH; ++g) {
    const int v0 = qv[g & 3][0];
    const int v1 = qv[g & 3][1];
    if (g < NCH - 4) {                       // qw refill, 4 chunks ahead
      qv[g & 3][0] = qwl[(size_t)(g + 4) * 4 * NN];
      qv[g & 3][1] = qwl[(size_t)(g + 4) * 4 * NN + 16];
    }
    if (g < NCH - 3) {                       // B-frag prefetch, 3 chunks ahead
      #pragma unroll
      for (int mt = 0; mt < 4; ++mt)
        bf[(g + 3) & 3][mt] = xb[bb + (g + 3) * 256 + mt * 16];
    }
    if ((g & 3) == 0 && (g >> 2) < 3) {      // scales/zeros, 1 group ahead
      const int gl = (g >> 2) + 1;
      const int gg = g0 + gl;
      ps[gl & 1][0] = scales[(size_t)gg * NN + ncol0];
      ps[gl & 1][1] = scales[(size_t)gg * NN + ncol0 + 16];
      const int zd0 = qz[(size_t)gg * NZROW + (ncol0 >> 3)];
      const int zd1 = qz[(size_t)gg * NZROW + (ncol0 >> 3) + 2];
      Cs[gl & 1][0] = (float)(0x800000 + 1) + (float)((zd0 >> zsh) & 15);
      Cs[gl & 1][1] = (float)(0x800000 + 1) + (float)((zd1 >> zsh) & 15);
    }

    const int gl = (g >> 2) & 1;
    const float sa = ps[gl][0], Ca = Cs[gl][0];
    const float sb = ps[gl][1], Cb = Cs[gl][1];
    // exact dequant: qf=(nib|0x4B000000)=2^23+q; d=qf-C (Sterbenz: q-z-1);
    // w=s*d; truncating bf16 pack (one v_perm per pair)
    i32x4 b0, b1;
    {
      const float w0 = sa * (__int_as_float(((v0      ) & 15) | 0x4B000000) - Ca);
      const float w1 = sa * (__int_as_float(((v0 >>  4) & 15) | 0x4B000000) - Ca);
      const float w2 = sa * (__int_as_float(((v0 >>  8) & 15) | 0x4B000000) - Ca);
      const float w3 = sa * (__int_as_float(((v0 >> 12) & 15) | 0x4B000000) - Ca);
      const float w4 = sa * (__int_as_float(((v0 >> 16) & 15) | 0x4B000000) - Ca);
      const float w5 = sa * (__int_as_float(((v0 >> 20) & 15) | 0x4B000000) - Ca);
      const float w6 = sa * (__int_as_float(((v0 >> 24) & 15) | 0x4B000000) - Ca);
      const float w7 = sa * (__int_as_float(((v0 >> 28) & 15) | 0x4B000000) - Ca);
      b0.x = perm_trunc(w0, w1); b0.y = perm_trunc(w2, w3);
      b0.z = perm_trunc(w4, w5); b0.w = perm_trunc(w6, w7);
    }
    {
      const float w0 = sb * (__int_as_float(((v1      ) & 15) | 0x4B000000) - Cb);
      const float w1 = sb * (__int_as_float(((v1 >>  4) & 15) | 0x4B000000) - Cb);
      const float w2 = sb * (__int_as_float(((v1 >>  8) & 15) | 0x4B000000) - Cb);
      const float w3 = sb * (__int_as_float(((v1 >> 12) & 15) | 0x4B000000) - Cb);
      const float w4 = sb * (__int_as_float(((v1 >> 16) & 15) | 0x4B000000) - Cb);
      const float w5 = sb * (__int_as_float(((v1 >> 20) & 15) | 0x4B000000) - Cb);
      const float w6 = sb * (__int_as_float(((v1 >> 24) & 15) | 0x4B000000) - Cb);
      const float w7 = sb * (__int_as_float(((v1 >> 28) & 15) | 0x4B000000) - Cb);
      b1.x = perm_trunc(w0, w1); b1.y = perm_trunc(w2, w3);
      b1.z = perm_trunc(w4, w5); b1.w = perm_trunc(w6, w7);
    }
    const s16x8 wf0 = __builtin_bit_cast(s16x8, b0);
    const s16x8 wf1 = __builtin_bit_cast(s16x8, b1);

    #pragma unroll
    for (int mt = 0; mt < 4; ++mt) {
      acc[0][mt] = __builtin_amdgcn_mfma_f32_16x16x32_bf16(wf0, bf[g & 3][mt], acc[0][mt], 0, 0, 0);
      acc[1][mt] = __builtin_amdgcn_mfma_f32_16x16x32_bf16(wf1, bf[g & 3][mt], acc[1][mt], 0, 0, 0);
    }
  }

  // ---- epilogue ----
  if (ATOMIC) {
    #pragma unroll
    for (int ns = 0; ns < 2; ++ns)
      #pragma unroll
      for (int mt = 0; mt < 4; ++mt) {
        const int m  = mt * 16 + ml;
        const int nb = nw0 + ns * 16 + quad * 4;
        const f32x4 a = acc[ns][mt];
        atomicAdd(&outws[(size_t)m * NN + nb + 0], a.x);
        atomicAdd(&outws[(size_t)m * NN + nb + 1], a.y);
        atomicAdd(&outws[(size_t)m * NN + nb + 2], a.z);
        atomicAdd(&outws[(size_t)m * NN + nb + 3], a.w);
      }
  } else {
    float* wsb = outws + (size_t)blockIdx.x * BLK_FLOATS;
    #pragma unroll
    for (int ns = 0; ns < 2; ++ns)
      #pragma unroll
      for (int mt = 0; mt < 4; ++mt)
        *(f32x4*)(wsb + ((wave * 8 + ns * 4 + mt) * 64 + lane) * 4) = acc[ns][mt];
  }
}

} // namespace

extern "C" void kernel_launch(void* const* d_in, const int* in_sizes, int n_in,
                              void* d_out, int out_size, void* d_ws, size_t ws_size,
                              hipStream_t stream) {
  const float* x      = (const float*)d_in[0];
  const int*   qw     = (const int*)d_in[1];
  const int*   qz     = (const int*)d_in[2];
  const float* scales = (const float*)d_in[3];
  const float* bias   = (const float*)d_in[4];
  float* out = (float*)d_out;

  xt8_kernel<<<2 * MM, 256, 0, stream>>>(x);
  if (ws_size >= WS_NEED) {
    float* ws = (float*)d_ws;
    gptq_gemm_kernel<false><<<NTILES * KSPLIT, 256, 0, stream>>>(qw, qz, scales, ws);
    reduce_kernel<<<(MM * NN) / 1024, 256, 0, stream>>>(ws, bias, out);
  } else {
    prep_kernel<<<(MM * NN) / 256, 256, 0, stream>>>(bias, out);
    gptq_gemm_kernel<true><<<NTILES * KSPLIT, 256, 0, stream>>>(qw, qz, scales, out);
  }
}